// Round 2
// baseline (520.412 us; speedup 1.0000x reference)
//
#include <hip/hip_runtime.h>
#include <hip/hip_bf16.h>
#include <math.h>

// Problem constants (fixed by reference file)
#define B_DIM    16
#define D_DIM    1024
#define F_DIM    128         // 2K features
#define N_MAXLEN 8192

// Tile config: each block computes 128 m-rows x 64 d-cols
#define BM   128
#define BN   64
#define SBS  136             // sB row stride in shorts (128 + 8 pad)
#define STS  68              // sT row stride in floats (64 + 4 pad)

typedef __attribute__((ext_vector_type(8))) short bf16x8;   // MFMA A/B frag (4 VGPRs)
typedef __attribute__((ext_vector_type(4))) float f32x4;    // MFMA C/D frag

union BF2 { __hip_bfloat162 h; unsigned u; };
union FRAG { unsigned u[4]; bf16x8 v; };

// out[m, d] = sum_f feats[m, f] * W[d, f],  feats interleaved (cos,sin)*0.125
// amp 0.125 is folded into the W->bf16 conversion instead.
__global__ __launch_bounds__(256, 4) void cyclic_gemm_kernel(
    const int* __restrict__ lengths,
    const float* __restrict__ W,      // [D_DIM][F_DIM] fp32 row-major
    float* __restrict__ out)          // [B*N][D_DIM] fp32
{
    // 17408 B, dual-purpose: bf16 W-tile during GEMM, fp32 out-tile (64 rows) in epilogue
    __shared__ __align__(16) char smem[BN * SBS * 2];
    short* sB = (short*)smem;
    float* sT = (float*)smem;

    const int tid = threadIdx.x;
    const int m0  = blockIdx.y * BM;
    const int d0  = blockIdx.x * BN;
    const int b   = m0 >> 13;                 // 128 | 8192, so one b per block
    const int n0  = m0 & (N_MAXLEN - 1);
    const int len = lengths[b];

    // ---- Fill sB: W[d0..d0+63][0..127] fp32 -> bf16 * 0.125, float4 coalesced ----
    {
        const float4* Wv = (const float4*)(W + (size_t)d0 * F_DIM);
        #pragma unroll
        for (int i = 0; i < 8; ++i) {
            const int lin = tid + i * 256;    // 0..2047 float4 slots (64 rows x 32)
            const int row = lin >> 5;
            const int c4  = lin & 31;
            const float4 w = Wv[lin];
            BF2 p0, p1;
            p0.h = __float22bfloat162_rn(make_float2(w.x * 0.125f, w.y * 0.125f));
            p1.h = __float22bfloat162_rn(make_float2(w.z * 0.125f, w.w * 0.125f));
            unsigned* p = (unsigned*)&sB[row * SBS + c4 * 4];
            p[0] = p0.u; p[1] = p1.u;
        }
    }

    const int lane = tid & 63;
    const int wave = tid >> 6;
    const int lrow = lane & 15;
    const int quad = lane >> 4;

    // ---- A-fragments in registers (overlaps with sB global-load latency) ----
    // Wave covers rows wave*32 .. wave*32+31 (mi chunks of 16).
    // A-frag element f = ks*32 + quad*8 + j; freq = f/2, parity = cos/sin.
    // rev = n*(kf+1)/len with base=n/len < 1 (exact-ish), fract, then HW sin/cos
    // which take REVOLUTIONS (v_sin_f32 computes sin(2*pi*x)).
    bf16x8 af[2][4];                          // [mi][ks]
    #pragma unroll
    for (int mi = 0; mi < 2; ++mi) {
        const int n     = n0 + wave * 32 + mi * 16 + lrow;
        const bool valid = n < len;
        const float base = (float)n / (float)len;
        #pragma unroll
        for (int ks = 0; ks < 4; ++ks) {
            FRAG f;
            #pragma unroll
            for (int p = 0; p < 4; ++p) {
                const float kf1 = (float)(ks * 16 + quad * 4 + p + 1);
                float rev = base * kf1;
                rev -= floorf(rev);
                const float c = __builtin_amdgcn_cosf(rev);
                const float s = __builtin_amdgcn_sinf(rev);
                BF2 cs; cs.h = __float22bfloat162_rn(make_float2(c, s));
                f.u[p] = valid ? cs.u : 0u;
            }
            af[mi][ks] = f.v;
        }
    }

    f32x4 acc[2][4];
    #pragma unroll
    for (int mi = 0; mi < 2; ++mi)
        #pragma unroll
        for (int ni = 0; ni < 4; ++ni)
            acc[mi][ni] = (f32x4){0.f, 0.f, 0.f, 0.f};

    __syncthreads();

    // ---- K-loop: K=128 in 4 steps of 32; per step 4 B-frags, 8 MFMAs ----
    #pragma unroll
    for (int ks = 0; ks < 4; ++ks) {
        bf16x8 bf[4];
        #pragma unroll
        for (int ni = 0; ni < 4; ++ni)
            bf[ni] = *(const bf16x8*)&sB[(ni * 16 + lrow) * SBS + ks * 32 + quad * 8];
        #pragma unroll
        for (int mi = 0; mi < 2; ++mi)
            #pragma unroll
            for (int ni = 0; ni < 4; ++ni)
                acc[mi][ni] = __builtin_amdgcn_mfma_f32_16x16x32_bf16(
                    af[mi][ks], bf[ni], acc[mi][ni], 0, 0, 0);
    }

    // ---- Epilogue: transpose via LDS (reuse sB space) in two 64-row halves,
    //      then float4 coalesced stores (256B contiguous per 16 lanes) ----
    #pragma unroll
    for (int h = 0; h < 2; ++h) {
        __syncthreads();                      // h=0: K-loop reads done; h=1: half0 reads done
        if ((wave >> 1) == h) {               // waves 2h, 2h+1 own rows h*64 .. h*64+63
            const int rbase = (wave & 1) * 32;
            #pragma unroll
            for (int mi = 0; mi < 2; ++mi)
                #pragma unroll
                for (int ni = 0; ni < 4; ++ni)
                    #pragma unroll
                    for (int reg = 0; reg < 4; ++reg)
                        sT[(rbase + mi * 16 + quad * 4 + reg) * STS + lrow + ni * 16]
                            = acc[mi][ni][reg];
        }
        __syncthreads();
        #pragma unroll
        for (int i = 0; i < 4; ++i) {
            const int idx = tid + i * 256;    // 0..1023 float4 slots (64 rows x 16)
            const int row = idx >> 4;
            const int c4  = idx & 15;
            const f32x4 v = *(const f32x4*)&sT[row * STS + c4 * 4];
            *(f32x4*)&out[(size_t)(m0 + h * 64 + row) * D_DIM + d0 + c4 * 4] = v;
        }
    }
}

__global__ void mask_kernel(const int* __restrict__ lengths, float* __restrict__ maskp) {
    const int i = blockIdx.x * blockDim.x + threadIdx.x;   // 0 .. B*N-1
    const int b = i >> 13;
    const int n = i & (N_MAXLEN - 1);
    maskp[i] = (n < lengths[b]) ? 1.0f : 0.0f;
}

extern "C" void kernel_launch(void* const* d_in, const int* in_sizes, int n_in,
                              void* d_out, int out_size, void* d_ws, size_t ws_size,
                              hipStream_t stream) {
    const int*   lengths = (const int*)d_in[0];
    const float* W       = (const float*)d_in[1];
    float* out   = (float*)d_out;
    float* maskp = out + (size_t)B_DIM * N_MAXLEN * D_DIM;

    dim3 grid(D_DIM / BN, (B_DIM * N_MAXLEN) / BM);   // (16, 1024)
    cyclic_gemm_kernel<<<grid, dim3(256), 0, stream>>>(lengths, W, out);

    const int mtot = B_DIM * N_MAXLEN;
    mask_kernel<<<mtot / 256, dim3(256), 0, stream>>>(lengths, maskp);
}